// Round 3
// baseline (468.846 us; speedup 1.0000x reference)
//
#include <hip/hip_runtime.h>

// ================= preprocessing =================

// zero cnt[R*N] histogram + pool partials
__global__ void k_init(int* cnt, unsigned int* pool_u32, int RN) {
    int i = blockIdx.x * blockDim.x + threadIdx.x;
    if (i < RN) cnt[i] = 0;
    if (i < 32 * 64 * 2) pool_u32[i] = 0u;   // 32x64 doubles
}

// histogram over (dst, src-range)
__global__ void k_hist(const int* __restrict__ src, const int* __restrict__ dst, int E,
                       int* __restrict__ cnt, int R, int Q) {
    int e = blockIdx.x * blockDim.x + threadIdx.x;
    if (e >= E) return;
    int s = src[e];
    int r = 0, th = Q;
    for (int k = 1; k < R; ++k) { r += (s >= th); th += Q; }
    atomicAdd(&cnt[dst[e] * R + r], 1);
}

// block sums of per-node degree (deg = sum of R bucket counts)
__global__ void k_scanA(const int* __restrict__ cnt, int N, int R, int* __restrict__ blockSums) {
    __shared__ int s[256];
    int t = threadIdx.x, i = blockIdx.x * 256 + t;
    int d = 0;
    if (i < N) for (int r = 0; r < R; ++r) d += cnt[i * R + r];
    s[t] = d;
    __syncthreads();
    for (int o = 128; o > 0; o >>= 1) {
        if (t < o) s[t] += s[t + o];
        __syncthreads();
    }
    if (t == 0) blockSums[blockIdx.x] = s[0];
}

// exclusive scan of block sums (single block, nb <= 256)
__global__ void k_scan2(int* blockSums, int nb) {
    __shared__ int s[256];
    int t = threadIdx.x;
    s[t] = (t < nb) ? blockSums[t] : 0;
    __syncthreads();
    for (int o = 1; o < 256; o <<= 1) {
        int v = (t >= o) ? s[t - o] : 0;
        __syncthreads();
        s[t] += v;
        __syncthreads();
    }
    blockSums[t] = (t == 0) ? 0 : s[t - 1];
}

// rowptr / bucket rowptr8+cursor8 / dinv
__global__ void k_scanC(const int* __restrict__ cnt, int N, int R,
                        const int* __restrict__ blockOffs,
                        int* __restrict__ rowptr, int* __restrict__ rowptr8,
                        int* __restrict__ cursor8, float* __restrict__ dinv) {
    __shared__ int s[256];
    int t = threadIdx.x, i = blockIdx.x * 256 + t;
    int d = 0;
    if (i < N) for (int r = 0; r < R; ++r) d += cnt[i * R + r];
    s[t] = d;
    __syncthreads();
    for (int o = 1; o < 256; o <<= 1) {
        int v = (t >= o) ? s[t - o] : 0;
        __syncthreads();
        s[t] += v;
        __syncthreads();
    }
    if (i < N) {
        int p = blockOffs[blockIdx.x] + s[t] - d;   // exclusive prefix
        rowptr[i] = p;
        dinv[i] = 1.0f / sqrtf((float)(d + 1));     // +1 self loop
        int pp = p;
        for (int r = 0; r < R; ++r) {
            rowptr8[i * R + r] = pp;
            cursor8[i * R + r] = pp;
            pp += cnt[i * R + r];
        }
        if (i == N - 1) rowptr[N] = p + d;
    }
}

// CSR fill bucketed by (dst, src-range)
__global__ void k_fill2(const int* __restrict__ src, const int* __restrict__ dst, int E,
                        int* __restrict__ cursor8, int* __restrict__ col, int R, int Q) {
    int e = blockIdx.x * blockDim.x + threadIdx.x;
    if (e >= E) return;
    int s = src[e];
    int r = 0, th = Q;
    for (int k = 1; k < R; ++k) { r += (s >= th); th += Q; }
    int pos = atomicAdd(&cursor8[dst[e] * R + r], 1);
    col[pos] = s;
}

// gx = dinv (x)  pre-scaled input rows
__global__ void k_gx(const float* __restrict__ x, const float* __restrict__ dinv,
                     float* __restrict__ gx, int N10) {
    int i = blockIdx.x * blockDim.x + threadIdx.x;
    if (i < N10) gx[i] = x[i] * dinv[i / 10];
}

// ================= layer 1 (fused, x is L2-resident) =================
__global__ void k_layer1(const float* __restrict__ gx, const float* __restrict__ W1,
                         const float* __restrict__ b1, const int* __restrict__ rowptr,
                         const int* __restrict__ col, const float* __restrict__ dinv,
                         float* __restrict__ g1, int N) {
    __shared__ float sW[10 * 64];
    __shared__ float sB[64];
    int t = threadIdx.x;
    for (int i = t; i < 10 * 64; i += 256) sW[i] = W1[i];
    if (t < 64) sB[t] = b1[t];
    __syncthreads();
    int wid = (blockIdx.x * 256 + t) >> 6;
    int lane = t & 63;
    if (wid >= N) return;
    const bool act = lane < 10;
    float di = dinv[wid];
    float ax = act ? gx[wid * 10 + lane] : 0.f;   // self loop (pre-scaled)
    int s0 = rowptr[wid], s1 = rowptr[wid + 1];
    int e = s0;
    for (; e + 8 <= s1; e += 8) {
        int j0 = col[e], j1 = col[e+1], j2 = col[e+2], j3 = col[e+3];
        int j4 = col[e+4], j5 = col[e+5], j6 = col[e+6], j7 = col[e+7];
        float v0=0.f,v1=0.f,v2=0.f,v3=0.f,v4=0.f,v5=0.f,v6=0.f,v7=0.f;
        if (act) {
            v0 = gx[j0*10+lane]; v1 = gx[j1*10+lane]; v2 = gx[j2*10+lane]; v3 = gx[j3*10+lane];
            v4 = gx[j4*10+lane]; v5 = gx[j5*10+lane]; v6 = gx[j6*10+lane]; v7 = gx[j7*10+lane];
        }
        ax += ((v0+v1)+(v2+v3)) + ((v4+v5)+(v6+v7));
    }
    for (; e < s1; ++e) {
        int j = col[e];
        float v = act ? gx[j*10+lane] : 0.f;
        ax += v;
    }
    float a1 = di * ax;                  // P_i(x)[lane] for lane<10
    float acc = sB[lane];
    #pragma unroll
    for (int k = 0; k < 10; ++k)
        acc += __shfl(a1, k, 64) * sW[k * 64 + lane];
    float h = fmaxf(acc, 0.f);
    g1[(size_t)wid * 64 + lane] = di * h;
}

// ================= range-partitioned gather =================
// block b -> (range r = b & (R-1), node chunk c = b >> logR). All waves of a
// dispatch-slice with the same r gather only from a N/R-node slice of g
// (~1.6 MB for R=8) -> L2-resident per XCD (b%8 round-robin heuristic).
__global__ void k_gatherR(const float* __restrict__ g, const int* __restrict__ rowptr,
                          const int* __restrict__ rowptr8, const int* __restrict__ col,
                          float* __restrict__ partial, int N, int R, int logR) {
    int t = threadIdx.x;
    int b = blockIdx.x;
    int r = b & (R - 1);
    int c = b >> logR;
    int node = c * 4 + (t >> 6);
    int lane = t & 63;
    if (node >= N) return;
    int s0 = rowptr8[node * R + r];
    int s1 = (r == R - 1) ? rowptr[node + 1] : rowptr8[node * R + r + 1];
    float acc = 0.f;
    int e = s0;
    for (; e + 4 <= s1; e += 4) {
        int j0 = col[e], j1 = col[e+1], j2 = col[e+2], j3 = col[e+3];
        float v0 = g[(size_t)j0 * 64 + lane];
        float v1 = g[(size_t)j1 * 64 + lane];
        float v2 = g[(size_t)j2 * 64 + lane];
        float v3 = g[(size_t)j3 * 64 + lane];
        acc += (v0 + v1) + (v2 + v3);
    }
    for (; e < s1; ++e) acc += g[(size_t)col[e] * 64 + lane];
    partial[((size_t)r * N + node) * 64 + lane] = acc;
}

// ================= reduce partials + transform (layer 1->2, 2->3 weights) =================
__global__ void k_reduceW(const float* __restrict__ partial, const float* __restrict__ gself,
                          const float* __restrict__ W, const float* __restrict__ b,
                          const float* __restrict__ dinv, float* __restrict__ gout,
                          int N, int R) {
    __shared__ float sW[64 * 64];
    __shared__ float sB[64];
    int t = threadIdx.x;
    for (int i = t; i < 64 * 64; i += 256) sW[i] = W[i];
    if (t < 64) sB[t] = b[t];
    __syncthreads();
    int node = (blockIdx.x * 256 + t) >> 6;
    int lane = t & 63;
    if (node >= N) return;
    size_t base = (size_t)node * 64;
    float acc = gself[base + lane];          // self loop (pre-scaled)
    for (int r = 0; r < R; ++r)
        acc += partial[((size_t)r * N + node) * 64 + lane];
    float di = dinv[node];
    float a = di * acc;                      // P_i(h)[lane]
    float s = sB[lane];
    #pragma unroll
    for (int k = 0; k < 64; ++k)
        s += __shfl(a, k, 64) * sW[k * 64 + lane];
    float h = fmaxf(s, 0.f);
    gout[base + lane] = di * h;
}

// ================= reduce partials + mean-pool (layer 3) =================
__global__ void k_reduce3(const float* __restrict__ partial, const float* __restrict__ gself,
                          const float* __restrict__ dinv, double* __restrict__ pool,
                          int N, int R) {
    __shared__ float sred[256];
    int t = threadIdx.x;
    int node = (blockIdx.x * 256 + t) >> 6;
    int lane = t & 63;
    float a3 = 0.f;
    if (node < N) {
        size_t base = (size_t)node * 64;
        float acc = gself[base + lane];
        for (int r = 0; r < R; ++r)
            acc += partial[((size_t)r * N + node) * 64 + lane];
        a3 = dinv[node] * acc;
    }
    sred[t] = a3;
    __syncthreads();
    if (t < 128) sred[t] += sred[t + 128];
    __syncthreads();
    if (t < 64) {
        float v = sred[t] + sred[t + 64];
        atomicAdd(&pool[(blockIdx.x & 31) * 64 + t], (double)v);
    }
}

// ================= final: out = mean(P(h2)) @ (W3@fcW) + b3@fcW + fcb =================
__global__ void k_final(const double* __restrict__ pool, const float* __restrict__ W3,
                        const float* __restrict__ fcW, const float* __restrict__ b3,
                        const float* __restrict__ fcb, float* __restrict__ out, double invN) {
    int f = threadIdx.x;   // 64 threads, one wave
    double p = 0.0;
    for (int s = 0; s < 32; ++s) p += pool[s * 64 + f];
    float pm = (float)(p * invN);
    float w = 0.f;
    #pragma unroll 8
    for (int j = 0; j < 64; ++j) w += W3[f * 64 + j] * fcW[j];
    float contrib = pm * w + b3[f] * fcW[f];
    for (int o = 32; o > 0; o >>= 1) contrib += __shfl_down(contrib, o, 64);
    if (f == 0) out[0] = contrib + fcb[0];
}

extern "C" void kernel_launch(void* const* d_in, const int* in_sizes, int n_in,
                              void* d_out, int out_size, void* d_ws, size_t ws_size,
                              hipStream_t stream) {
    const float* x   = (const float*)d_in[0];
    const int*   ei  = (const int*)d_in[1];
    const float* W1  = (const float*)d_in[2];
    const float* b1  = (const float*)d_in[3];
    const float* W2  = (const float*)d_in[4];
    const float* b2  = (const float*)d_in[5];
    const float* W3  = (const float*)d_in[6];
    const float* b3  = (const float*)d_in[7];
    const float* fcW = (const float*)d_in[8];
    const float* fcb = (const float*)d_in[9];

    const int N = in_sizes[0] / 10;
    const int E = in_sizes[1] / 2;
    const int* src = ei;
    const int* dst = ei + E;

    auto A = [](size_t b) { return (b + 255) & ~(size_t)255; };

    // choose largest R in {8,4,2,1} that fits ws
    int R = 1, logR = 0;
    for (int cand = 8; cand >= 1; cand >>= 1) {
        size_t fixed = A((size_t)N * 4)           // dinv
                     + A((size_t)(N + 1) * 4)     // rowptr
                     + A((size_t)cand * N * 4)    // rowptr8
                     + A((size_t)E * 4)           // col
                     + A(256 * 4)                 // blockSums
                     + A(32 * 64 * 8)             // pool
                     + A((size_t)N * 64 * 4) * 2; // g1, g2
        size_t pregion = A((size_t)cand * N * 4) * 2 + A((size_t)N * 10 * 4); // cnt+cursor+gx
        size_t part = A((size_t)cand * N * 64 * 4);
        size_t P = part > pregion ? part : pregion;
        if (fixed + P <= ws_size) {
            R = cand;
            logR = (cand == 8) ? 3 : (cand == 4) ? 2 : (cand == 2) ? 1 : 0;
            break;
        }
    }
    const int Q = (N + R - 1) / R;

    // ---- workspace carve-up ----
    char* w = (char*)d_ws;
    size_t off = 0;
    auto alloc = [&](size_t bytes) -> void* {
        void* p = w + off;
        off += (bytes + 255) & ~(size_t)255;
        return p;
    };
    float*  dinv      = (float*)alloc((size_t)N * 4);
    int*    rowptr    = (int*)alloc((size_t)(N + 1) * 4);
    int*    rowptr8   = (int*)alloc((size_t)R * N * 4);
    int*    col       = (int*)alloc((size_t)E * 4);
    int*    blockSums = (int*)alloc(256 * 4);
    double* pool      = (double*)alloc(32 * 64 * 8);
    float*  g1        = (float*)alloc((size_t)N * 64 * 4);
    float*  g2        = (float*)alloc((size_t)N * 64 * 4);
    // P region: partial overlays {cnt, cursor8, gx} (disjoint lifetimes)
    char*   Pbase     = (char*)(w + off);
    float*  partial   = (float*)Pbase;
    int*    cnt       = (int*)Pbase;
    int*    cursor8   = (int*)(Pbase + A((size_t)R * N * 4));
    float*  gx        = (float*)(Pbase + 2 * A((size_t)R * N * 4));
    (void)ws_size; (void)n_in; (void)out_size;

    const int RN         = R * N;
    const int nbScan     = (N + 255) / 256;
    const int nbEdges    = (E + 255) / 256;
    const int nodeChunks = (N + 3) / 4;           // 4 node-waves per 256-block
    const int nbInit     = ((RN > 4096 ? RN : 4096) + 255) / 256;
    const int nbGx       = (N * 10 + 255) / 256;

    // ---- graph preprocessing ----
    k_init <<<nbInit, 256, 0, stream>>>(cnt, (unsigned int*)pool, RN);
    k_hist <<<nbEdges, 256, 0, stream>>>(src, dst, E, cnt, R, Q);
    k_scanA<<<nbScan, 256, 0, stream>>>(cnt, N, R, blockSums);
    k_scan2<<<1, 256, 0, stream>>>(blockSums, nbScan);
    k_scanC<<<nbScan, 256, 0, stream>>>(cnt, N, R, blockSums, rowptr, rowptr8, cursor8, dinv);
    k_fill2<<<nbEdges, 256, 0, stream>>>(src, dst, E, cursor8, col, R, Q);
    k_gx   <<<nbGx, 256, 0, stream>>>(x, dinv, gx, N * 10);

    // ---- layer 1 (fused; x slice is L2-resident at 2 MB) ----
    k_layer1<<<nodeChunks, 256, 0, stream>>>(gx, W1, b1, rowptr, col, dinv, g1, N);

    // ---- layer 2: range gather -> partials -> reduce + @W2 ----
    k_gatherR<<<nodeChunks * R, 256, 0, stream>>>(g1, rowptr, rowptr8, col, partial, N, R, logR);
    k_reduceW<<<nodeChunks, 256, 0, stream>>>(partial, g1, W2, b2, dinv, g2, N, R);

    // ---- layer 3: range gather -> partials -> reduce + pool ----
    k_gatherR<<<nodeChunks * R, 256, 0, stream>>>(g2, rowptr, rowptr8, col, partial, N, R, logR);
    k_reduce3<<<nodeChunks, 256, 0, stream>>>(partial, g2, dinv, pool, N, R);

    k_final<<<1, 64, 0, stream>>>(pool, W3, fcW, b3, fcb, (float*)d_out, 1.0 / (double)N);
}

// Round 4
// 423.651 us; speedup vs baseline: 1.1067x; 1.1067x over previous
//
#include <hip/hip_runtime.h>

// ================= preprocessing =================

// zero cnt[R*N] histogram + pool partials (256 doubles = 512 u32)
__global__ void k_init(int* cnt, unsigned int* pool_u32, int RN) {
    int i = blockIdx.x * blockDim.x + threadIdx.x;
    if (i < RN) cnt[i] = 0;
    if (i < 512) pool_u32[i] = 0u;
}

// histogram over (dst, src-range)
__global__ void k_hist(const int* __restrict__ src, const int* __restrict__ dst, int E,
                       int* __restrict__ cnt, int R, int Q) {
    int e = blockIdx.x * blockDim.x + threadIdx.x;
    if (e >= E) return;
    int s = src[e];
    int r = 0, th = Q;
    for (int k = 1; k < R; ++k) { r += (s >= th); th += Q; }
    atomicAdd(&cnt[dst[e] * R + r], 1);
}

// block sums of per-node degree
__global__ void k_scanA(const int* __restrict__ cnt, int N, int R, int* __restrict__ blockSums) {
    __shared__ int s[256];
    int t = threadIdx.x, i = blockIdx.x * 256 + t;
    int d = 0;
    if (i < N) for (int r = 0; r < R; ++r) d += cnt[i * R + r];
    s[t] = d;
    __syncthreads();
    for (int o = 128; o > 0; o >>= 1) {
        if (t < o) s[t] += s[t + o];
        __syncthreads();
    }
    if (t == 0) blockSums[blockIdx.x] = s[0];
}

// exclusive scan of block sums (single block, nb <= 256)
__global__ void k_scan2(int* blockSums, int nb) {
    __shared__ int s[256];
    int t = threadIdx.x;
    s[t] = (t < nb) ? blockSums[t] : 0;
    __syncthreads();
    for (int o = 1; o < 256; o <<= 1) {
        int v = (t >= o) ? s[t - o] : 0;
        __syncthreads();
        s[t] += v;
        __syncthreads();
    }
    blockSums[t] = (t == 0) ? 0 : s[t - 1];
}

// rowptr / bucket rowptr + cursor / dinv
__global__ void k_scanC(const int* __restrict__ cnt, int N, int R,
                        const int* __restrict__ blockOffs,
                        int* __restrict__ rowptr, int* __restrict__ rowptrR,
                        int* __restrict__ cursorR, float* __restrict__ dinv) {
    __shared__ int s[256];
    int t = threadIdx.x, i = blockIdx.x * 256 + t;
    int d = 0;
    if (i < N) for (int r = 0; r < R; ++r) d += cnt[i * R + r];
    s[t] = d;
    __syncthreads();
    for (int o = 1; o < 256; o <<= 1) {
        int v = (t >= o) ? s[t - o] : 0;
        __syncthreads();
        s[t] += v;
        __syncthreads();
    }
    if (i < N) {
        int p = blockOffs[blockIdx.x] + s[t] - d;   // exclusive prefix
        rowptr[i] = p;
        dinv[i] = 1.0f / sqrtf((float)(d + 1));     // +1 self loop
        int pp = p;
        for (int r = 0; r < R; ++r) {
            rowptrR[i * R + r] = pp;
            cursorR[i * R + r] = pp;
            pp += cnt[i * R + r];
        }
        if (i == N - 1) rowptr[N] = p + d;
    }
}

// CSR fill bucketed by (dst, src-range)
__global__ void k_fill2(const int* __restrict__ src, const int* __restrict__ dst, int E,
                        int* __restrict__ cursorR, int* __restrict__ col, int R, int Q) {
    int e = blockIdx.x * blockDim.x + threadIdx.x;
    if (e >= E) return;
    int s = src[e];
    int r = 0, th = Q;
    for (int k = 1; k < R; ++k) { r += (s >= th); th += Q; }
    int pos = atomicAdd(&cursorR[dst[e] * R + r], 1);
    col[pos] = s;
}

// ================= pre-transform: gw0 = dinv * (x @ W1) =================
__global__ void k_pre(const float* __restrict__ x, const float* __restrict__ W1,
                      const float* __restrict__ dinv, float* __restrict__ g, int N) {
    __shared__ float sW[10 * 64];
    int t = threadIdx.x;
    for (int i = t; i < 640; i += 256) sW[i] = W1[i];
    __syncthreads();
    int node = (blockIdx.x * 256 + t) >> 6, lane = t & 63;
    if (node >= N) return;
    float acc = 0.f;
    #pragma unroll
    for (int k = 0; k < 10; ++k) acc += x[node * 10 + k] * sW[k * 64 + lane];
    __builtin_nontemporal_store(dinv[node] * acc, &g[(size_t)node * 64 + lane]);
}

// ================= XCD-pinned range gather (self loop folded in-slice) =================
// r = b & (R-1): with round-robin block->XCD, each XCD serves one L2-resident slice.
// Partial stores are nontemporal so they don't evict the slice.
__global__ void k_gatherR(const float* __restrict__ g, const int* __restrict__ rowptr,
                          const int* __restrict__ rowptrR, const int* __restrict__ col,
                          float* __restrict__ partial, int N, int R, int logR, int Q) {
    int t = threadIdx.x;
    int b = blockIdx.x;
    int r = b & (R - 1);
    int c = b >> logR;
    int node = c * 4 + (t >> 6);
    int lane = t & 63;
    if (node >= N) return;
    int s0 = rowptrR[node * R + r];
    int s1 = (r == R - 1) ? rowptr[node + 1] : rowptrR[node * R + r + 1];
    int lo = r * Q;
    float acc = (node >= lo && node < lo + Q) ? g[(size_t)node * 64 + lane] : 0.f;
    int e = s0;
    for (; e + 4 <= s1; e += 4) {
        int j0 = col[e], j1 = col[e + 1], j2 = col[e + 2], j3 = col[e + 3];
        float v0 = g[(size_t)j0 * 64 + lane];
        float v1 = g[(size_t)j1 * 64 + lane];
        float v2 = g[(size_t)j2 * 64 + lane];
        float v3 = g[(size_t)j3 * 64 + lane];
        acc += (v0 + v1) + (v2 + v3);
    }
    for (; e < s1; ++e) acc += g[(size_t)col[e] * 64 + lane];
    __builtin_nontemporal_store(acc, &partial[((size_t)r * N + node) * 64 + lane]);
}

// ================= reduce partials; epilogue relu(+b) then fold next W =================
// gout = dinv * (relu(dinv*sum + bias) @ W)
__global__ void k_reduceW(const float* __restrict__ partial, const float* __restrict__ W,
                          const float* __restrict__ bias, const float* __restrict__ dinv,
                          float* __restrict__ gout, int N, int R) {
    __shared__ float sW[64 * 64];
    __shared__ float sB[64];
    int t = threadIdx.x;
    for (int i = t; i < 64 * 64; i += 256) sW[i] = W[i];
    if (t < 64) sB[t] = bias[t];
    __syncthreads();
    int node = (blockIdx.x * 256 + t) >> 6, lane = t & 63;
    if (node >= N) return;
    float acc = 0.f;
    for (int r = 0; r < R; ++r)
        acc += __builtin_nontemporal_load(&partial[((size_t)r * N + node) * 64 + lane]);
    float di = dinv[node];
    float h = fmaxf(di * acc + sB[lane], 0.f);
    float s = 0.f;
    #pragma unroll
    for (int k = 0; k < 64; ++k)
        s += __shfl(h, k, 64) * sW[k * 64 + lane];
    __builtin_nontemporal_store(di * s, &gout[(size_t)node * 64 + lane]);
}

// ================= reduce partials; epilogue relu(+b) then scalar t = di*(h . wfc) ======
__global__ void k_reduceT(const float* __restrict__ partial, const float* __restrict__ wfc,
                          const float* __restrict__ bias, const float* __restrict__ dinv,
                          float* __restrict__ tvec, int N, int R) {
    int t = threadIdx.x;
    int node = (blockIdx.x * 256 + t) >> 6, lane = t & 63;
    if (node >= N) return;
    float acc = 0.f;
    for (int r = 0; r < R; ++r)
        acc += __builtin_nontemporal_load(&partial[((size_t)r * N + node) * 64 + lane]);
    float di = dinv[node];
    float h = fmaxf(di * acc + bias[lane], 0.f);
    float p = h * wfc[lane];
    for (int o = 32; o > 0; o >>= 1) p += __shfl_down(p, o, 64);
    if (lane == 0) tvec[node] = di * p;
}

// ================= tiny: wfc = W3 @ fcW, wfc[64] = b3 . fcW =================
__global__ void k_wfc(const float* __restrict__ W3, const float* __restrict__ fcW,
                      const float* __restrict__ b3, float* __restrict__ wfc) {
    int f = threadIdx.x;   // 64
    float s = 0.f;
    #pragma unroll 8
    for (int j = 0; j < 64; ++j) s += W3[f * 64 + j] * fcW[j];
    wfc[f] = s;
    float bb = b3[f] * fcW[f];
    for (int o = 32; o > 0; o >>= 1) bb += __shfl_down(bb, o, 64);
    if (f == 0) wfc[64] = bb;
}

// ================= layer-3 scalar gather + pool (t is 200KB: L2-resident) =================
__global__ void k_agg3(const float* __restrict__ tvec, const int* __restrict__ rowptr,
                       const int* __restrict__ col, const float* __restrict__ dinv,
                       double* __restrict__ pool, int N) {
    int tid = blockIdx.x * 256 + threadIdx.x;
    int node = tid >> 6, lane = tid & 63;
    if (node >= N) return;
    int s0 = rowptr[node], s1 = rowptr[node + 1];
    float s = 0.f;
    for (int e = s0 + lane; e < s1; e += 64) s += tvec[col[e]];
    for (int o = 32; o > 0; o >>= 1) s += __shfl_down(s, o, 64);
    if (lane == 0) {
        double contrib = (double)(dinv[node] * (tvec[node] + s));
        atomicAdd(&pool[(tid >> 6) & 255], contrib);
    }
}

// ================= final =================
__global__ void k_final(const double* __restrict__ pool, const float* __restrict__ wfc,
                        const float* __restrict__ fcb, float* __restrict__ out, double invN) {
    __shared__ double s[256];
    int t = threadIdx.x;
    s[t] = pool[t];
    __syncthreads();
    for (int o = 128; o > 0; o >>= 1) {
        if (t < o) s[t] += s[t + o];
        __syncthreads();
    }
    if (t == 0) out[0] = (float)(s[0] * invN) + wfc[64] + fcb[0];
}

extern "C" void kernel_launch(void* const* d_in, const int* in_sizes, int n_in,
                              void* d_out, int out_size, void* d_ws, size_t ws_size,
                              hipStream_t stream) {
    const float* x   = (const float*)d_in[0];
    const int*   ei  = (const int*)d_in[1];
    const float* W1  = (const float*)d_in[2];
    const float* b1  = (const float*)d_in[3];
    const float* W2  = (const float*)d_in[4];
    const float* b2  = (const float*)d_in[5];
    const float* W3  = (const float*)d_in[6];
    const float* b3  = (const float*)d_in[7];
    const float* fcW = (const float*)d_in[8];
    const float* fcb = (const float*)d_in[9];

    const int N = in_sizes[0] / 10;
    const int E = in_sizes[1] / 2;
    const int* src = ei;
    const int* dst = ei + E;

    auto A = [](size_t b) { return (b + 255) & ~(size_t)255; };

    // choose largest R in {4,2,1} that fits ws (R=4: slice 3.2MB < 4MB L2, partials halved)
    int R = 1, logR = 0;
    for (int cand = 4; cand >= 1; cand >>= 1) {
        size_t fixed = A((size_t)N * 4)             // dinv
                     + A((size_t)(N + 1) * 4)       // rowptr
                     + A((size_t)cand * N * 4)      // rowptrR
                     + A((size_t)E * 4)             // col
                     + A(256 * 4)                   // blockSums
                     + A(256 * 8)                   // pool
                     + A(65 * 4)                    // wfc
                     + A((size_t)N * 4)             // tvec
                     + A((size_t)N * 64 * 4);       // g
        size_t pregion = A((size_t)cand * N * 4) * 2;              // cnt + cursor overlay
        size_t part = A((size_t)cand * N * 64 * 4);                // partial
        size_t P = part > pregion ? part : pregion;
        if (fixed + P <= ws_size) {
            R = cand;
            logR = (cand == 4) ? 2 : (cand == 2) ? 1 : 0;
            break;
        }
    }
    const int Q = (N + R - 1) / R;

    // ---- workspace carve-up ----
    char* w = (char*)d_ws;
    size_t off = 0;
    auto alloc = [&](size_t bytes) -> void* {
        void* p = w + off;
        off += (bytes + 255) & ~(size_t)255;
        return p;
    };
    float*  dinv      = (float*)alloc((size_t)N * 4);
    int*    rowptr    = (int*)alloc((size_t)(N + 1) * 4);
    int*    rowptrR   = (int*)alloc((size_t)R * N * 4);
    int*    col       = (int*)alloc((size_t)E * 4);
    int*    blockSums = (int*)alloc(256 * 4);
    double* pool      = (double*)alloc(256 * 8);
    float*  wfc       = (float*)alloc(65 * 4);
    float*  tvec      = (float*)alloc((size_t)N * 4);
    float*  g         = (float*)alloc((size_t)N * 64 * 4);
    // P region: partial overlays {cnt, cursorR} (disjoint lifetimes)
    char*   Pbase     = (char*)(w + off);
    float*  partial   = (float*)Pbase;
    int*    cnt       = (int*)Pbase;
    int*    cursorR   = (int*)(Pbase + A((size_t)R * N * 4));
    (void)n_in; (void)out_size;

    const int RN         = R * N;
    const int nbScan     = (N + 255) / 256;
    const int nbEdges    = (E + 255) / 256;
    const int nodeChunks = (N + 3) / 4;           // 4 node-waves per 256-block
    const int nbInit     = ((RN > 512 ? RN : 512) + 255) / 256;

    // ---- graph preprocessing ----
    k_init <<<nbInit, 256, 0, stream>>>(cnt, (unsigned int*)pool, RN);
    k_hist <<<nbEdges, 256, 0, stream>>>(src, dst, E, cnt, R, Q);
    k_scanA<<<nbScan, 256, 0, stream>>>(cnt, N, R, blockSums);
    k_scan2<<<1, 256, 0, stream>>>(blockSums, nbScan);
    k_scanC<<<nbScan, 256, 0, stream>>>(cnt, N, R, blockSums, rowptr, rowptrR, cursorR, dinv);
    k_fill2<<<nbEdges, 256, 0, stream>>>(src, dst, E, cursorR, col, R, Q);
    k_wfc  <<<1, 64, 0, stream>>>(W3, fcW, b3, wfc);

    // ---- layer 1: pre-transform, gather, reduce(+fold W2) ----
    k_pre<<<nodeChunks, 256, 0, stream>>>(x, W1, dinv, g, N);
    k_gatherR<<<nodeChunks * R, 256, 0, stream>>>(g, rowptr, rowptrR, col, partial, N, R, logR, Q);
    k_reduceW<<<nodeChunks, 256, 0, stream>>>(partial, W2, b1, dinv, g, N, R);

    // ---- layer 2: gather, reduce -> per-node scalar t (wfc folded) ----
    k_gatherR<<<nodeChunks * R, 256, 0, stream>>>(g, rowptr, rowptrR, col, partial, N, R, logR, Q);
    k_reduceT<<<nodeChunks, 256, 0, stream>>>(partial, wfc, b2, dinv, tvec, N, R);

    // ---- layer 3: scalar gather + pool ----
    k_agg3<<<nodeChunks, 256, 0, stream>>>(tvec, rowptr, col, dinv, pool, N);
    k_final<<<1, 256, 0, stream>>>(pool, wfc, fcb, (float*)d_out, 1.0 / (double)N);
}

// Round 5
// 304.711 us; speedup vs baseline: 1.5387x; 1.3903x over previous
//
#include <hip/hip_runtime.h>
#include <hip/hip_fp16.h>

// ================= preprocessing =================

__global__ void k_init(int* cnt, unsigned long long* pool_bits, int N) {
    int i = blockIdx.x * blockDim.x + threadIdx.x;
    if (i < N) cnt[i] = 0;
    if (i < 256) pool_bits[i] = 0ull;   // 256 doubles
}

__global__ void k_deg(const int* __restrict__ dst, int E, int* __restrict__ cnt) {
    int e = blockIdx.x * blockDim.x + threadIdx.x;
    if (e < E) atomicAdd(&cnt[dst[e]], 1);
}

__global__ void k_scanA(const int* __restrict__ cnt, int N, int* __restrict__ blockSums) {
    __shared__ int s[256];
    int t = threadIdx.x, i = blockIdx.x * 256 + t;
    s[t] = (i < N) ? cnt[i] : 0;
    __syncthreads();
    for (int o = 128; o > 0; o >>= 1) {
        if (t < o) s[t] += s[t + o];
        __syncthreads();
    }
    if (t == 0) blockSums[blockIdx.x] = s[0];
}

__global__ void k_scan2(int* blockSums, int nb) {
    __shared__ int s[256];
    int t = threadIdx.x;
    s[t] = (t < nb) ? blockSums[t] : 0;
    __syncthreads();
    for (int o = 1; o < 256; o <<= 1) {
        int v = (t >= o) ? s[t - o] : 0;
        __syncthreads();
        s[t] += v;
        __syncthreads();
    }
    blockSums[t] = (t == 0) ? 0 : s[t - 1];
}

__global__ void k_scanC(const int* __restrict__ cnt, int N, const int* __restrict__ blockOffs,
                        int* __restrict__ rowptr, int* __restrict__ cursor,
                        float* __restrict__ dinv) {
    __shared__ int s[256];
    int t = threadIdx.x, i = blockIdx.x * 256 + t;
    int d = (i < N) ? cnt[i] : 0;
    s[t] = d;
    __syncthreads();
    for (int o = 1; o < 256; o <<= 1) {
        int v = (t >= o) ? s[t - o] : 0;
        __syncthreads();
        s[t] += v;
        __syncthreads();
    }
    if (i < N) {
        int p = blockOffs[blockIdx.x] + s[t] - d;
        rowptr[i] = p;
        cursor[i] = p;
        dinv[i] = 1.0f / sqrtf((float)(d + 1));
        if (i == N - 1) rowptr[N] = p + d;
    }
}

__global__ void k_fill(const int* __restrict__ src, const int* __restrict__ dst, int E,
                       int* __restrict__ cursor, int* __restrict__ col) {
    int e = blockIdx.x * blockDim.x + threadIdx.x;
    if (e < E) {
        int pos = atomicAdd(&cursor[dst[e]], 1);
        col[pos] = src[e];
    }
}

// wfc[c] = (W3 @ fcW)[c], wfc[64] = b3 . fcW
__global__ void k_wfc(const float* __restrict__ W3, const float* __restrict__ fcW,
                      const float* __restrict__ b3, float* __restrict__ wfc) {
    int f = threadIdx.x;   // 64
    float s = 0.f;
    #pragma unroll 8
    for (int j = 0; j < 64; ++j) s += W3[f * 64 + j] * fcW[j];
    wfc[f] = s;
    float bb = b3[f] * fcW[f];
    for (int o = 32; o > 0; o >>= 1) bb += __shfl_down(bb, o, 64);
    if (f == 0) wfc[64] = bb;
}

// gx = fp16( dinv (.) x )
__global__ void k_gx(const float* __restrict__ x, const float* __restrict__ dinv,
                     __half* __restrict__ gx, int N10) {
    int i = blockIdx.x * blockDim.x + threadIdx.x;
    if (i < N10) gx[i] = __float2half(x[i] * dinv[i / 10]);
}

// ================= layer 1: gather gx (1MB, L2-resident), 4 nodes/wave =================
// lanes: f = t&15 (features 0..9 active in gather), group of 16 per node.
// epilogue: h1 = relu(P(x)@W1 + b1); g1 = fp16(dinv*h1); lane writes c = 4f..4f+3.
__global__ void k_L1(const __half* __restrict__ gx, const float* __restrict__ W1,
                     const float* __restrict__ b1, const int* __restrict__ rowptr,
                     const int* __restrict__ col, const float* __restrict__ dinv,
                     __half* __restrict__ g1, int N) {
    __shared__ float sW[10 * 64];
    __shared__ float sB[64];
    int t = threadIdx.x;
    for (int i = t; i < 640; i += 256) sW[i] = W1[i];
    if (t < 64) sB[t] = b1[t];
    __syncthreads();
    int node = blockIdx.x * 16 + (t >> 4);
    int f = t & 15;
    bool live = node < N;
    bool act = live && (f < 10);
    float di = live ? dinv[node] : 0.f;
    float a = act ? __half2float(gx[node * 10 + f]) : 0.f;   // self (pre-scaled)
    int s0 = 0, s1 = 0;
    if (live) { s0 = rowptr[node]; s1 = rowptr[node + 1]; }
    int e = s0;
    for (; e + 2 <= s1; e += 2) {
        int j0 = col[e], j1 = col[e + 1];
        float v0 = act ? __half2float(gx[j0 * 10 + f]) : 0.f;
        float v1 = act ? __half2float(gx[j1 * 10 + f]) : 0.f;
        a += v0 + v1;
    }
    if (e < s1) {
        int j = col[e];
        if (act) a += __half2float(gx[j * 10 + f]);
    }
    a *= di;                                   // P_i(x)[f], f<10
    int gb = t & 48;                           // group base lane within wave
    float c0 = 0.f, c1 = 0.f, c2 = 0.f, c3 = 0.f;
    int c4 = 4 * f;
    #pragma unroll
    for (int k = 0; k < 10; ++k) {
        float ak = __shfl(a, gb + k, 64);
        c0 += ak * sW[k * 64 + c4];
        c1 += ak * sW[k * 64 + c4 + 1];
        c2 += ak * sW[k * 64 + c4 + 2];
        c3 += ak * sW[k * 64 + c4 + 3];
    }
    if (!live) return;
    float h0 = di * fmaxf(c0 + sB[c4], 0.f);
    float h1 = di * fmaxf(c1 + sB[c4 + 1], 0.f);
    float h2 = di * fmaxf(c2 + sB[c4 + 2], 0.f);
    float h3 = di * fmaxf(c3 + sB[c4 + 3], 0.f);
    union { __half h[4]; uint2 u; } pk;
    pk.h[0] = __float2half(h0); pk.h[1] = __float2half(h1);
    pk.h[2] = __float2half(h2); pk.h[3] = __float2half(h3);
    *reinterpret_cast<uint2*>(&g1[(size_t)node * 64 + c4]) = pk.u;
}

// ================= layer 2: gather g1 (6.4MB fp16) + @W2 + relu + wfc-dot -> tvec ========
__global__ void k_L2(const __half* __restrict__ g1, const float* __restrict__ W2,
                     const float* __restrict__ b2, const float* __restrict__ wfc,
                     const int* __restrict__ rowptr, const int* __restrict__ col,
                     const float* __restrict__ dinv, float* __restrict__ tvec, int N) {
    __shared__ float sW[64 * 64];
    __shared__ float sB[64];
    __shared__ float sF[64];
    int t = threadIdx.x;
    for (int i = t; i < 4096; i += 256) sW[i] = W2[i];
    if (t < 64) { sB[t] = b2[t]; sF[t] = wfc[t]; }
    __syncthreads();
    int node = (blockIdx.x * 256 + t) >> 6, lane = t & 63;
    if (node >= N) return;
    size_t base = (size_t)node * 64;
    float acc = __half2float(g1[base + lane]);     // self loop (pre-scaled)
    int s0 = rowptr[node], s1 = rowptr[node + 1];
    int e = s0;
    for (; e + 4 <= s1; e += 4) {
        int j0 = col[e], j1 = col[e + 1], j2 = col[e + 2], j3 = col[e + 3];
        float v0 = __half2float(g1[(size_t)j0 * 64 + lane]);
        float v1 = __half2float(g1[(size_t)j1 * 64 + lane]);
        float v2 = __half2float(g1[(size_t)j2 * 64 + lane]);
        float v3 = __half2float(g1[(size_t)j3 * 64 + lane]);
        acc += (v0 + v1) + (v2 + v3);
    }
    for (; e < s1; ++e) acc += __half2float(g1[(size_t)col[e] * 64 + lane]);
    float di = dinv[node];
    float a = di * acc;                            // P_i(h1)[lane]
    float s = sB[lane];
    #pragma unroll
    for (int k = 0; k < 64; ++k)
        s += __shfl(a, k, 64) * sW[k * 64 + lane];
    float h = fmaxf(s, 0.f);                       // h2[lane]
    float p = h * sF[lane];
    for (int o = 32; o > 0; o >>= 1) p += __shfl_down(p, o, 64);
    if (lane == 0) tvec[node] = di * p;            // t_j = dinv_j * (h2_j . wfc)
}

// ================= layer 3: scalar gather over tvec (200KB) + mean-pool =================
__global__ void k_agg3(const float* __restrict__ tvec, const int* __restrict__ rowptr,
                       const int* __restrict__ col, const float* __restrict__ dinv,
                       double* __restrict__ pool, int N) {
    int tid = blockIdx.x * 256 + threadIdx.x;
    int node = tid >> 6, lane = tid & 63;
    if (node >= N) return;
    int s0 = rowptr[node], s1 = rowptr[node + 1];
    float s = 0.f;
    for (int e = s0 + lane; e < s1; e += 64) s += tvec[col[e]];
    for (int o = 32; o > 0; o >>= 1) s += __shfl_down(s, o, 64);
    if (lane == 0) {
        double contrib = (double)(dinv[node] * (tvec[node] + s));
        atomicAdd(&pool[node & 255], contrib);
    }
}

__global__ void k_final(const double* __restrict__ pool, const float* __restrict__ wfc,
                        const float* __restrict__ fcb, float* __restrict__ out, double invN) {
    __shared__ double s[256];
    int t = threadIdx.x;
    s[t] = pool[t];
    __syncthreads();
    for (int o = 128; o > 0; o >>= 1) {
        if (t < o) s[t] += s[t + o];
        __syncthreads();
    }
    if (t == 0) out[0] = (float)(s[0] * invN) + wfc[64] + fcb[0];
}

extern "C" void kernel_launch(void* const* d_in, const int* in_sizes, int n_in,
                              void* d_out, int out_size, void* d_ws, size_t ws_size,
                              hipStream_t stream) {
    const float* x   = (const float*)d_in[0];
    const int*   ei  = (const int*)d_in[1];
    const float* W1  = (const float*)d_in[2];
    const float* b1  = (const float*)d_in[3];
    const float* W2  = (const float*)d_in[4];
    const float* b2  = (const float*)d_in[5];
    const float* W3  = (const float*)d_in[6];
    const float* b3  = (const float*)d_in[7];
    const float* fcW = (const float*)d_in[8];
    const float* fcb = (const float*)d_in[9];

    const int N = in_sizes[0] / 10;
    const int E = in_sizes[1] / 2;
    const int* src = ei;
    const int* dst = ei + E;

    // ---- workspace carve-up (256B aligned; ~12 MB total) ----
    char* w = (char*)d_ws;
    size_t off = 0;
    auto alloc = [&](size_t bytes) -> void* {
        void* p = w + off;
        off += (bytes + 255) & ~(size_t)255;
        return p;
    };
    int*    cnt       = (int*)alloc((size_t)N * 4);
    float*  dinv      = (float*)alloc((size_t)N * 4);
    int*    rowptr    = (int*)alloc((size_t)(N + 1) * 4);
    int*    cursor    = (int*)alloc((size_t)N * 4);
    int*    col       = (int*)alloc((size_t)E * 4);
    int*    blockSums = (int*)alloc(256 * 4);
    double* pool      = (double*)alloc(256 * 8);
    float*  wfc       = (float*)alloc(65 * 4);
    float*  tvec      = (float*)alloc((size_t)N * 4);
    __half* gx        = (__half*)alloc((size_t)N * 10 * 2);
    __half* g1        = (__half*)alloc((size_t)N * 64 * 2);
    (void)ws_size; (void)n_in; (void)out_size;

    const int nbScan     = (N + 255) / 256;
    const int nbEdges    = (E + 255) / 256;
    const int nodeChunks = (N + 3) / 4;       // 4 node-waves per 256-block
    const int l1Blocks   = (N + 15) / 16;     // 16 nodes per 256-block
    const int nbGx       = (N * 10 + 255) / 256;

    // ---- preprocessing ----
    k_init <<<nbScan, 256, 0, stream>>>(cnt, (unsigned long long*)pool, N);
    k_deg  <<<nbEdges, 256, 0, stream>>>(dst, E, cnt);
    k_scanA<<<nbScan, 256, 0, stream>>>(cnt, N, blockSums);
    k_scan2<<<1, 256, 0, stream>>>(blockSums, nbScan);
    k_scanC<<<nbScan, 256, 0, stream>>>(cnt, N, blockSums, rowptr, cursor, dinv);
    k_fill <<<nbEdges, 256, 0, stream>>>(src, dst, E, cursor, col);
    k_wfc  <<<1, 64, 0, stream>>>(W3, fcW, b3, wfc);
    k_gx   <<<nbGx, 256, 0, stream>>>(x, dinv, gx, N * 10);

    // ---- fused layers ----
    k_L1<<<l1Blocks, 256, 0, stream>>>(gx, W1, b1, rowptr, col, dinv, g1, N);
    k_L2<<<nodeChunks, 256, 0, stream>>>(g1, W2, b2, wfc, rowptr, col, dinv, tvec, N);
    k_agg3<<<nodeChunks, 256, 0, stream>>>(tvec, rowptr, col, dinv, pool, N);
    k_final<<<1, 256, 0, stream>>>(pool, wfc, fcb, (float*)d_out, 1.0 / (double)N);
}

// Round 6
// 224.389 us; speedup vs baseline: 2.0894x; 1.3580x over previous
//
#include <hip/hip_runtime.h>
#include <hip/hip_fp16.h>

typedef _Float16 half8 __attribute__((ext_vector_type(8)));
typedef float float4v __attribute__((ext_vector_type(4)));

// ================= preprocessing =================

__global__ void k_init(int* cnt, unsigned long long* pool_bits, int N) {
    int i = blockIdx.x * blockDim.x + threadIdx.x;
    if (i < N) cnt[i] = 0;
    if (i < 256) pool_bits[i] = 0ull;   // 256 doubles
}

__global__ void k_deg(const int* __restrict__ dst, int E, int* __restrict__ cnt) {
    int e = blockIdx.x * blockDim.x + threadIdx.x;
    if (e < E) atomicAdd(&cnt[dst[e]], 1);
}

__global__ void k_scanA(const int* __restrict__ cnt, int N, int* __restrict__ blockSums) {
    __shared__ int s[256];
    int t = threadIdx.x, i = blockIdx.x * 256 + t;
    s[t] = (i < N) ? cnt[i] : 0;
    __syncthreads();
    for (int o = 128; o > 0; o >>= 1) {
        if (t < o) s[t] += s[t + o];
        __syncthreads();
    }
    if (t == 0) blockSums[blockIdx.x] = s[0];
}

__global__ void k_scan2(int* blockSums, int nb) {
    __shared__ int s[256];
    int t = threadIdx.x;
    s[t] = (t < nb) ? blockSums[t] : 0;
    __syncthreads();
    for (int o = 1; o < 256; o <<= 1) {
        int v = (t >= o) ? s[t - o] : 0;
        __syncthreads();
        s[t] += v;
        __syncthreads();
    }
    blockSums[t] = (t == 0) ? 0 : s[t - 1];
}

// rowptr / cursor / dinv / gx = fp16(dinv (.) x)
__global__ void k_scanC(const int* __restrict__ cnt, int N, const int* __restrict__ blockOffs,
                        const float* __restrict__ x,
                        int* __restrict__ rowptr, int* __restrict__ cursor,
                        float* __restrict__ dinv, __half* __restrict__ gx) {
    __shared__ int s[256];
    int t = threadIdx.x, i = blockIdx.x * 256 + t;
    int d = (i < N) ? cnt[i] : 0;
    s[t] = d;
    __syncthreads();
    for (int o = 1; o < 256; o <<= 1) {
        int v = (t >= o) ? s[t - o] : 0;
        __syncthreads();
        s[t] += v;
        __syncthreads();
    }
    if (i < N) {
        int p = blockOffs[blockIdx.x] + s[t] - d;
        rowptr[i] = p;
        cursor[i] = p;
        float di = 1.0f / sqrtf((float)(d + 1));
        dinv[i] = di;
        #pragma unroll
        for (int k = 0; k < 10; ++k)
            gx[i * 10 + k] = __float2half(x[i * 10 + k] * di);
        if (i == N - 1) rowptr[N] = p + d;
    }
}

__global__ void k_fill(const int* __restrict__ src, const int* __restrict__ dst, int E,
                       int* __restrict__ cursor, int* __restrict__ col) {
    int e = blockIdx.x * blockDim.x + threadIdx.x;
    if (e < E) {
        int pos = atomicAdd(&cursor[dst[e]], 1);
        col[pos] = src[e];
    }
}

// wfc[c] = (W3 @ fcW)[c], wfc[64] = b3 . fcW
__global__ void k_wfc(const float* __restrict__ W3, const float* __restrict__ fcW,
                      const float* __restrict__ b3, float* __restrict__ wfc) {
    int f = threadIdx.x;   // 64
    float s = 0.f;
    #pragma unroll 8
    for (int j = 0; j < 64; ++j) s += W3[f * 64 + j] * fcW[j];
    wfc[f] = s;
    float bb = b3[f] * fcW[f];
    for (int o = 32; o > 0; o >>= 1) bb += __shfl_down(bb, o, 64);
    if (f == 0) wfc[64] = bb;
}

// ================= layer 1: gather gx (1MB, L2-resident), 4 nodes/wave =================
__global__ void k_L1(const __half* __restrict__ gx, const float* __restrict__ W1,
                     const float* __restrict__ b1, const int* __restrict__ rowptr,
                     const int* __restrict__ col, const float* __restrict__ dinv,
                     __half* __restrict__ g1, int N) {
    __shared__ float sW[10 * 64];
    __shared__ float sB[64];
    int t = threadIdx.x;
    for (int i = t; i < 640; i += 256) sW[i] = W1[i];
    if (t < 64) sB[t] = b1[t];
    __syncthreads();
    int node = blockIdx.x * 16 + (t >> 4);
    int f = t & 15;
    bool live = node < N;
    bool act = live && (f < 10);
    float di = live ? dinv[node] : 0.f;
    float a = act ? __half2float(gx[node * 10 + f]) : 0.f;   // self (pre-scaled)
    int s0 = 0, s1 = 0;
    if (live) { s0 = rowptr[node]; s1 = rowptr[node + 1]; }
    int e = s0;
    for (; e + 4 <= s1; e += 4) {
        int j0 = col[e], j1 = col[e + 1], j2 = col[e + 2], j3 = col[e + 3];
        float v0 = act ? __half2float(gx[j0 * 10 + f]) : 0.f;
        float v1 = act ? __half2float(gx[j1 * 10 + f]) : 0.f;
        float v2 = act ? __half2float(gx[j2 * 10 + f]) : 0.f;
        float v3 = act ? __half2float(gx[j3 * 10 + f]) : 0.f;
        a += (v0 + v1) + (v2 + v3);
    }
    for (; e < s1; ++e) {
        int j = col[e];
        if (act) a += __half2float(gx[j * 10 + f]);
    }
    a *= di;                                   // P_i(x)[f], f<10
    int gb = t & 48;                           // group base lane within wave
    float c0 = 0.f, c1 = 0.f, c2 = 0.f, c3 = 0.f;
    int c4 = 4 * f;
    #pragma unroll
    for (int k = 0; k < 10; ++k) {
        float ak = __shfl(a, gb + k, 64);
        c0 += ak * sW[k * 64 + c4];
        c1 += ak * sW[k * 64 + c4 + 1];
        c2 += ak * sW[k * 64 + c4 + 2];
        c3 += ak * sW[k * 64 + c4 + 3];
    }
    if (!live) return;
    float h0 = di * fmaxf(c0 + sB[c4], 0.f);
    float h1 = di * fmaxf(c1 + sB[c4 + 1], 0.f);
    float h2 = di * fmaxf(c2 + sB[c4 + 2], 0.f);
    float h3 = di * fmaxf(c3 + sB[c4 + 3], 0.f);
    union { __half h[4]; uint2 u; } pk;
    pk.h[0] = __float2half(h0); pk.h[1] = __float2half(h1);
    pk.h[2] = __float2half(h2); pk.h[3] = __float2half(h3);
    *reinterpret_cast<uint2*>(&g1[(size_t)node * 64 + c4]) = pk.u;
}

// ================= layer 2: 16 nodes/block, vector gather + MFMA epilogue =================
__device__ __forceinline__ void acc4(float* a, uint2 u) {
    __half2 h0 = *reinterpret_cast<__half2*>(&u.x);
    __half2 h1 = *reinterpret_cast<__half2*>(&u.y);
    float2 f0 = __half22float2(h0), f1 = __half22float2(h1);
    a[0] += f0.x; a[1] += f0.y; a[2] += f1.x; a[3] += f1.y;
}

__global__ void __launch_bounds__(256) k_L2(
        const __half* __restrict__ g1, const float* __restrict__ W2,
        const float* __restrict__ b2, const float* __restrict__ wfc,
        const int* __restrict__ rowptr, const int* __restrict__ col,
        const float* __restrict__ dinv, float* __restrict__ tvec, int N) {
    __shared__ __half At[16 * 72];     // 16 nodes x 64 feats, stride 72 (bank-safe b128 reads)
    __shared__ float sRed[4][16];
    __shared__ float sDi[16];
    int t = threadIdx.x;
    int lane = t & 63, wid = t >> 6;
    int m = lane & 15, quad = lane >> 4;

    // ---- B fragments: W2 column cg, fp16 hi/lo split (in registers, overlap gather) ----
    int cg = (wid << 4) + m;            // output feature this lane covers
    half8 H0, L0, H1, L1;
    #pragma unroll
    for (int j = 0; j < 8; ++j) {
        float w0 = W2[(quad * 8 + j) * 64 + cg];
        _Float16 h0 = (_Float16)w0;
        H0[j] = h0; L0[j] = (_Float16)(w0 - (float)h0);
        float w1 = W2[(32 + quad * 8 + j) * 64 + cg];
        _Float16 h1 = (_Float16)w1;
        H1[j] = h1; L1[j] = (_Float16)(w1 - (float)h1);
    }
    float bc = b2[cg], wf = wfc[cg];

    // ---- gather: node nl = t>>4 (16/block), lane f4 = t&15 handles 4 feats ----
    int nl = t >> 4, f4 = t & 15;
    int node = blockIdx.x * 16 + nl;
    bool live = node < N;
    float di = live ? dinv[node] : 0.f;
    float a[4] = {0.f, 0.f, 0.f, 0.f};
    if (live) {
        const uint2* self = (const uint2*)(g1 + ((size_t)node << 6) + (f4 << 2));
        acc4(a, *self);                                   // self loop (pre-scaled)
        int s0 = rowptr[node], s1 = rowptr[node + 1];
        int e = s0;
        for (; e + 4 <= s1; e += 4) {
            int j0 = col[e], j1 = col[e + 1], j2 = col[e + 2], j3 = col[e + 3];
            uint2 u0 = *(const uint2*)(g1 + ((size_t)j0 << 6) + (f4 << 2));
            uint2 u1 = *(const uint2*)(g1 + ((size_t)j1 << 6) + (f4 << 2));
            uint2 u2 = *(const uint2*)(g1 + ((size_t)j2 << 6) + (f4 << 2));
            uint2 u3 = *(const uint2*)(g1 + ((size_t)j3 << 6) + (f4 << 2));
            acc4(a, u0); acc4(a, u1); acc4(a, u2); acc4(a, u3);
        }
        for (; e < s1; ++e) {
            uint2 u = *(const uint2*)(g1 + ((size_t)col[e] << 6) + (f4 << 2));
            acc4(a, u);
        }
    }
    // a2 = di * acc -> fp16 into LDS A-tile
    union { __half h[4]; uint2 u; } pk;
    pk.h[0] = __float2half(a[0] * di); pk.h[1] = __float2half(a[1] * di);
    pk.h[2] = __float2half(a[2] * di); pk.h[3] = __float2half(a[3] * di);
    *reinterpret_cast<uint2*>(&At[nl * 72 + f4 * 4]) = pk.u;
    if (f4 == 0) sDi[nl] = di;
    __syncthreads();

    // ---- MFMA: D[m=node][n=col] = A(16x64) @ W2(64x64), this wave: cols 16*wid.. ----
    half8 A0 = *reinterpret_cast<const half8*>(&At[m * 72 + quad * 8]);        // k=quad*8+j
    half8 A1 = *reinterpret_cast<const half8*>(&At[m * 72 + 32 + quad * 8]);   // k=32+...
    float4v C = {0.f, 0.f, 0.f, 0.f};
    C = __builtin_amdgcn_mfma_f32_16x16x32_f16(A0, H0, C, 0, 0, 0);
    C = __builtin_amdgcn_mfma_f32_16x16x32_f16(A0, L0, C, 0, 0, 0);
    C = __builtin_amdgcn_mfma_f32_16x16x32_f16(A1, H1, C, 0, 0, 0);
    C = __builtin_amdgcn_mfma_f32_16x16x32_f16(A1, L1, C, 0, 0, 0);

    // ---- epilogue: relu(C + b2)*wfc, reduce over cols -> per-node scalar ----
    float v0 = fmaxf(C[0] + bc, 0.f) * wf;     // node quad*4+0
    float v1 = fmaxf(C[1] + bc, 0.f) * wf;
    float v2 = fmaxf(C[2] + bc, 0.f) * wf;
    float v3 = fmaxf(C[3] + bc, 0.f) * wf;
    #pragma unroll
    for (int o = 1; o < 16; o <<= 1) {
        v0 += __shfl_xor(v0, o, 64);
        v1 += __shfl_xor(v1, o, 64);
        v2 += __shfl_xor(v2, o, 64);
        v3 += __shfl_xor(v3, o, 64);
    }
    if (m == 0) {
        sRed[wid][quad * 4 + 0] = v0;
        sRed[wid][quad * 4 + 1] = v1;
        sRed[wid][quad * 4 + 2] = v2;
        sRed[wid][quad * 4 + 3] = v3;
    }
    __syncthreads();
    if (t < 16) {
        int ng = blockIdx.x * 16 + t;
        if (ng < N) {
            float tt = sRed[0][t] + sRed[1][t] + sRed[2][t] + sRed[3][t];
            tvec[ng] = sDi[t] * tt;            // t_j = dinv_j * (h2_j . wfc)
        }
    }
}

// ================= layer 3: scalar gather over tvec (200KB) + mean-pool =================
__global__ void k_agg3(const float* __restrict__ tvec, const int* __restrict__ rowptr,
                       const int* __restrict__ col, const float* __restrict__ dinv,
                       double* __restrict__ pool, int N) {
    int tid = blockIdx.x * 256 + threadIdx.x;
    int node = tid >> 4, lane = tid & 15;
    if (node >= N) return;
    int s0 = rowptr[node], s1 = rowptr[node + 1];
    float s = 0.f;
    for (int e = s0 + lane; e < s1; e += 16) s += tvec[col[e]];
    #pragma unroll
    for (int o = 1; o < 16; o <<= 1) s += __shfl_xor(s, o, 64);
    if (lane == 0) {
        double contrib = (double)(dinv[node] * (tvec[node] + s));
        atomicAdd(&pool[node & 255], contrib);
    }
}

__global__ void k_final(const double* __restrict__ pool, const float* __restrict__ wfc,
                        const float* __restrict__ fcb, float* __restrict__ out, double invN) {
    __shared__ double s[256];
    int t = threadIdx.x;
    s[t] = pool[t];
    __syncthreads();
    for (int o = 128; o > 0; o >>= 1) {
        if (t < o) s[t] += s[t + o];
        __syncthreads();
    }
    if (t == 0) out[0] = (float)(s[0] * invN) + wfc[64] + fcb[0];
}

extern "C" void kernel_launch(void* const* d_in, const int* in_sizes, int n_in,
                              void* d_out, int out_size, void* d_ws, size_t ws_size,
                              hipStream_t stream) {
    const float* x   = (const float*)d_in[0];
    const int*   ei  = (const int*)d_in[1];
    const float* W1  = (const float*)d_in[2];
    const float* b1  = (const float*)d_in[3];
    const float* W2  = (const float*)d_in[4];
    const float* b2  = (const float*)d_in[5];
    const float* W3  = (const float*)d_in[6];
    const float* b3  = (const float*)d_in[7];
    const float* fcW = (const float*)d_in[8];
    const float* fcb = (const float*)d_in[9];

    const int N = in_sizes[0] / 10;
    const int E = in_sizes[1] / 2;
    const int* src = ei;
    const int* dst = ei + E;

    // ---- workspace carve-up (256B aligned) ----
    char* w = (char*)d_ws;
    size_t off = 0;
    auto alloc = [&](size_t bytes) -> void* {
        void* p = w + off;
        off += (bytes + 255) & ~(size_t)255;
        return p;
    };
    int*    cnt       = (int*)alloc((size_t)N * 4);
    float*  dinv      = (float*)alloc((size_t)N * 4);
    int*    rowptr    = (int*)alloc((size_t)(N + 1) * 4);
    int*    cursor    = (int*)alloc((size_t)N * 4);
    int*    col       = (int*)alloc((size_t)E * 4);
    int*    blockSums = (int*)alloc(256 * 4);
    double* pool      = (double*)alloc(256 * 8);
    float*  wfc       = (float*)alloc(65 * 4);
    float*  tvec      = (float*)alloc((size_t)N * 4);
    __half* gx        = (__half*)alloc((size_t)N * 10 * 2);
    __half* g1        = (__half*)alloc((size_t)N * 64 * 2);
    (void)ws_size; (void)n_in; (void)out_size;

    const int nbScan   = (N + 255) / 256;
    const int nbEdges  = (E + 255) / 256;
    const int nbNode16 = (N + 15) / 16;       // 16 nodes per 256-block

    // ---- preprocessing ----
    k_init <<<nbScan, 256, 0, stream>>>(cnt, (unsigned long long*)pool, N);
    k_deg  <<<nbEdges, 256, 0, stream>>>(dst, E, cnt);
    k_scanA<<<nbScan, 256, 0, stream>>>(cnt, N, blockSums);
    k_scan2<<<1, 256, 0, stream>>>(blockSums, nbScan);
    k_scanC<<<nbScan, 256, 0, stream>>>(cnt, N, blockSums, x, rowptr, cursor, dinv, gx);
    k_fill <<<nbEdges, 256, 0, stream>>>(src, dst, E, cursor, col);
    k_wfc  <<<1, 64, 0, stream>>>(W3, fcW, b3, wfc);

    // ---- fused layers ----
    k_L1<<<nbNode16, 256, 0, stream>>>(gx, W1, b1, rowptr, col, dinv, g1, N);
    k_L2<<<nbNode16, 256, 0, stream>>>(g1, W2, b2, wfc, rowptr, col, dinv, tvec, N);
    k_agg3<<<nbNode16, 256, 0, stream>>>(tvec, rowptr, col, dinv, pool, N);
    k_final<<<1, 256, 0, stream>>>(pool, wfc, fcb, (float*)d_out, 1.0 / (double)N);
}

// Round 7
// 212.590 us; speedup vs baseline: 2.2054x; 1.0555x over previous
//
#include <hip/hip_runtime.h>
#include <hip/hip_fp16.h>

typedef _Float16 half8 __attribute__((ext_vector_type(8)));
typedef float float4v __attribute__((ext_vector_type(4)));

// ================= preprocessing =================

__global__ void k_deg(const int* __restrict__ dst, int E, int* __restrict__ cnt) {
    int e = blockIdx.x * blockDim.x + threadIdx.x;
    if (e < E) atomicAdd(&cnt[dst[e]], 1);
}

__global__ void k_scanA(const int* __restrict__ cnt, int N, int* __restrict__ blockSums) {
    __shared__ int s[256];
    int t = threadIdx.x, i = blockIdx.x * 256 + t;
    s[t] = (i < N) ? cnt[i] : 0;
    __syncthreads();
    for (int o = 128; o > 0; o >>= 1) {
        if (t < o) s[t] += s[t + o];
        __syncthreads();
    }
    if (t == 0) blockSums[blockIdx.x] = s[0];
}

__global__ void k_scan2(int* blockSums, int nb) {
    __shared__ int s[256];
    int t = threadIdx.x;
    s[t] = (t < nb) ? blockSums[t] : 0;
    __syncthreads();
    for (int o = 1; o < 256; o <<= 1) {
        int v = (t >= o) ? s[t - o] : 0;
        __syncthreads();
        s[t] += v;
        __syncthreads();
    }
    blockSums[t] = (t == 0) ? 0 : s[t - 1];
}

// rowptr / cursor / dinv / gx = fp16(dinv (.) x)
__global__ void k_scanC(const int* __restrict__ cnt, int N, const int* __restrict__ blockOffs,
                        const float* __restrict__ x,
                        int* __restrict__ rowptr, int* __restrict__ cursor,
                        float* __restrict__ dinv, __half* __restrict__ gx) {
    __shared__ int s[256];
    int t = threadIdx.x, i = blockIdx.x * 256 + t;
    int d = (i < N) ? cnt[i] : 0;
    s[t] = d;
    __syncthreads();
    for (int o = 1; o < 256; o <<= 1) {
        int v = (t >= o) ? s[t - o] : 0;
        __syncthreads();
        s[t] += v;
        __syncthreads();
    }
    if (i < N) {
        int p = blockOffs[blockIdx.x] + s[t] - d;
        rowptr[i] = p;
        cursor[i] = p;
        float di = 1.0f / sqrtf((float)(d + 1));
        dinv[i] = di;
        #pragma unroll
        for (int k = 0; k < 10; ++k)
            gx[i * 10 + k] = __float2half(x[i * 10 + k] * di);
        if (i == N - 1) rowptr[N] = p + d;
    }
}

// XCD-pinned CSR fill: range r = b&7 (round-robin block->XCD); each XCD's col
// writes land in a ~400KB L2-resident slice (CSR regions are contiguous per range).
__global__ void k_fillX(const int* __restrict__ src, const int* __restrict__ dst, int E,
                        int* __restrict__ cursor, int* __restrict__ col, int Q) {
    int b = blockIdx.x;
    int r = b & 7;
    int e = (b >> 3) * 256 + threadIdx.x;
    if (e >= E) return;
    int d = dst[e];
    int lo = r * Q;
    if (d < lo || d >= lo + Q) return;
    int pos = atomicAdd(&cursor[d], 1);
    col[pos] = src[e];
}

// wfc[c] = (W3 @ fcW)[c], wfc[64] = b3 . fcW
__global__ void k_wfc(const float* __restrict__ W3, const float* __restrict__ fcW,
                      const float* __restrict__ b3, float* __restrict__ wfc) {
    int f = threadIdx.x;   // 64
    float s = 0.f;
    #pragma unroll 8
    for (int j = 0; j < 64; ++j) s += W3[f * 64 + j] * fcW[j];
    wfc[f] = s;
    float bb = b3[f] * fcW[f];
    for (int o = 32; o > 0; o >>= 1) bb += __shfl_down(bb, o, 64);
    if (f == 0) wfc[64] = bb;
}

// ================= layer 1: gather gx (1MB, L2-resident), 16 lanes/node =================
__global__ void k_L1(const __half* __restrict__ gx, const float* __restrict__ W1,
                     const float* __restrict__ b1, const int* __restrict__ rowptr,
                     const int* __restrict__ col, const float* __restrict__ dinv,
                     __half* __restrict__ g1, int N) {
    __shared__ float sW[10 * 64];
    __shared__ float sB[64];
    int t = threadIdx.x;
    for (int i = t; i < 640; i += 256) sW[i] = W1[i];
    if (t < 64) sB[t] = b1[t];
    __syncthreads();
    int node = blockIdx.x * 16 + (t >> 4);
    int f = t & 15;
    bool live = node < N;
    bool act = live && (f < 10);
    float di = live ? dinv[node] : 0.f;
    float a = act ? __half2float(gx[node * 10 + f]) : 0.f;   // self (pre-scaled)
    int s0 = 0, s1 = 0;
    if (live) { s0 = rowptr[node]; s1 = rowptr[node + 1]; }
    int e = s0;
    for (; e + 4 <= s1; e += 4) {
        int j0 = col[e], j1 = col[e + 1], j2 = col[e + 2], j3 = col[e + 3];
        float v0 = act ? __half2float(gx[j0 * 10 + f]) : 0.f;
        float v1 = act ? __half2float(gx[j1 * 10 + f]) : 0.f;
        float v2 = act ? __half2float(gx[j2 * 10 + f]) : 0.f;
        float v3 = act ? __half2float(gx[j3 * 10 + f]) : 0.f;
        a += (v0 + v1) + (v2 + v3);
    }
    for (; e < s1; ++e) {
        int j = col[e];
        if (act) a += __half2float(gx[j * 10 + f]);
    }
    a *= di;                                   // P_i(x)[f], f<10
    int gb = t & 48;                           // group base lane within wave
    float c0 = 0.f, c1 = 0.f, c2 = 0.f, c3 = 0.f;
    int c4 = 4 * f;
    #pragma unroll
    for (int k = 0; k < 10; ++k) {
        float ak = __shfl(a, gb + k, 64);
        c0 += ak * sW[k * 64 + c4];
        c1 += ak * sW[k * 64 + c4 + 1];
        c2 += ak * sW[k * 64 + c4 + 2];
        c3 += ak * sW[k * 64 + c4 + 3];
    }
    if (!live) return;
    float h0 = di * fmaxf(c0 + sB[c4], 0.f);
    float h1 = di * fmaxf(c1 + sB[c4 + 1], 0.f);
    float h2 = di * fmaxf(c2 + sB[c4 + 2], 0.f);
    float h3 = di * fmaxf(c3 + sB[c4 + 3], 0.f);
    union { __half h[4]; uint2 u; } pk;
    pk.h[0] = __float2half(h0); pk.h[1] = __float2half(h1);
    pk.h[2] = __float2half(h2); pk.h[3] = __float2half(h3);
    *reinterpret_cast<uint2*>(&g1[(size_t)node * 64 + c4]) = pk.u;
}

// ================= layer 2: 16 nodes/block, vector gather + MFMA epilogue =================
__device__ __forceinline__ void acc4(float* a, uint2 u) {
    __half2 h0 = *reinterpret_cast<__half2*>(&u.x);
    __half2 h1 = *reinterpret_cast<__half2*>(&u.y);
    float2 f0 = __half22float2(h0), f1 = __half22float2(h1);
    a[0] += f0.x; a[1] += f0.y; a[2] += f1.x; a[3] += f1.y;
}

__global__ void __launch_bounds__(256) k_L2(
        const __half* __restrict__ g1, const float* __restrict__ W2,
        const float* __restrict__ b2, const float* __restrict__ wfc,
        const int* __restrict__ rowptr, const int* __restrict__ col,
        const float* __restrict__ dinv, float* __restrict__ tvec, int N) {
    __shared__ __half At[16 * 72];     // 16 nodes x 64 feats, stride 72 (bank-safe b128 reads)
    __shared__ float sRed[4][16];
    __shared__ float sDi[16];
    int t = threadIdx.x;
    int lane = t & 63, wid = t >> 6;
    int m = lane & 15, quad = lane >> 4;

    // ---- B fragments: W2 column cg, fp16 hi/lo split (in registers, overlap gather) ----
    int cg = (wid << 4) + m;            // output feature this lane covers
    half8 H0, L0, H1, L1;
    #pragma unroll
    for (int j = 0; j < 8; ++j) {
        float w0 = W2[(quad * 8 + j) * 64 + cg];
        _Float16 h0 = (_Float16)w0;
        H0[j] = h0; L0[j] = (_Float16)(w0 - (float)h0);
        float w1 = W2[(32 + quad * 8 + j) * 64 + cg];
        _Float16 h1 = (_Float16)w1;
        H1[j] = h1; L1[j] = (_Float16)(w1 - (float)h1);
    }
    float bc = b2[cg], wf = wfc[cg];

    // ---- gather: node nl = t>>4 (16/block), lane f4 = t&15 handles 4 feats ----
    int nl = t >> 4, f4 = t & 15;
    int node = blockIdx.x * 16 + nl;
    bool live = node < N;
    float di = live ? dinv[node] : 0.f;
    float a[4] = {0.f, 0.f, 0.f, 0.f};
    if (live) {
        const uint2* self = (const uint2*)(g1 + ((size_t)node << 6) + (f4 << 2));
        acc4(a, *self);                                   // self loop (pre-scaled)
        int s0 = rowptr[node], s1 = rowptr[node + 1];
        int e = s0;
        for (; e + 4 <= s1; e += 4) {
            int j0 = col[e], j1 = col[e + 1], j2 = col[e + 2], j3 = col[e + 3];
            uint2 u0 = *(const uint2*)(g1 + ((size_t)j0 << 6) + (f4 << 2));
            uint2 u1 = *(const uint2*)(g1 + ((size_t)j1 << 6) + (f4 << 2));
            uint2 u2 = *(const uint2*)(g1 + ((size_t)j2 << 6) + (f4 << 2));
            uint2 u3 = *(const uint2*)(g1 + ((size_t)j3 << 6) + (f4 << 2));
            acc4(a, u0); acc4(a, u1); acc4(a, u2); acc4(a, u3);
        }
        for (; e < s1; ++e) {
            uint2 u = *(const uint2*)(g1 + ((size_t)col[e] << 6) + (f4 << 2));
            acc4(a, u);
        }
    }
    // a2 = di * acc -> fp16 into LDS A-tile
    union { __half h[4]; uint2 u; } pk;
    pk.h[0] = __float2half(a[0] * di); pk.h[1] = __float2half(a[1] * di);
    pk.h[2] = __float2half(a[2] * di); pk.h[3] = __float2half(a[3] * di);
    *reinterpret_cast<uint2*>(&At[nl * 72 + f4 * 4]) = pk.u;
    if (f4 == 0) sDi[nl] = di;
    __syncthreads();

    // ---- MFMA: D[m=node][n=col] = A(16x64) @ W2(64x64), this wave: cols 16*wid.. ----
    half8 A0 = *reinterpret_cast<const half8*>(&At[m * 72 + quad * 8]);        // k=quad*8+j
    half8 A1 = *reinterpret_cast<const half8*>(&At[m * 72 + 32 + quad * 8]);   // k=32+...
    float4v C = {0.f, 0.f, 0.f, 0.f};
    C = __builtin_amdgcn_mfma_f32_16x16x32_f16(A0, H0, C, 0, 0, 0);
    C = __builtin_amdgcn_mfma_f32_16x16x32_f16(A0, L0, C, 0, 0, 0);
    C = __builtin_amdgcn_mfma_f32_16x16x32_f16(A1, H1, C, 0, 0, 0);
    C = __builtin_amdgcn_mfma_f32_16x16x32_f16(A1, L1, C, 0, 0, 0);

    // ---- epilogue: relu(C + b2)*wfc, reduce over cols -> per-node scalar ----
    float v0 = fmaxf(C[0] + bc, 0.f) * wf;     // node quad*4+0
    float v1 = fmaxf(C[1] + bc, 0.f) * wf;
    float v2 = fmaxf(C[2] + bc, 0.f) * wf;
    float v3 = fmaxf(C[3] + bc, 0.f) * wf;
    #pragma unroll
    for (int o = 1; o < 16; o <<= 1) {
        v0 += __shfl_xor(v0, o, 64);
        v1 += __shfl_xor(v1, o, 64);
        v2 += __shfl_xor(v2, o, 64);
        v3 += __shfl_xor(v3, o, 64);
    }
    if (m == 0) {
        sRed[wid][quad * 4 + 0] = v0;
        sRed[wid][quad * 4 + 1] = v1;
        sRed[wid][quad * 4 + 2] = v2;
        sRed[wid][quad * 4 + 3] = v3;
    }
    __syncthreads();
    if (t < 16) {
        int ng = blockIdx.x * 16 + t;
        if (ng < N) {
            float tt = sRed[0][t] + sRed[1][t] + sRed[2][t] + sRed[3][t];
            tvec[ng] = sDi[t] * tt;            // t_j = dinv_j * (h2_j . wfc)
        }
    }
}

// ================= layer 3: scalar gather over tvec (200KB) + mean-pool =================
__global__ void k_agg3(const float* __restrict__ tvec, const int* __restrict__ rowptr,
                       const int* __restrict__ col, const float* __restrict__ dinv,
                       double* __restrict__ pool, int N) {
    int tid = blockIdx.x * 256 + threadIdx.x;
    int node = tid >> 4, lane = tid & 15;
    if (node >= N) return;
    int s0 = rowptr[node], s1 = rowptr[node + 1];
    float s = 0.f;
    for (int e = s0 + lane; e < s1; e += 16) s += tvec[col[e]];
    #pragma unroll
    for (int o = 1; o < 16; o <<= 1) s += __shfl_xor(s, o, 64);
    if (lane == 0) {
        double contrib = (double)(dinv[node] * (tvec[node] + s));
        atomicAdd(&pool[node & 255], contrib);
    }
}

__global__ void k_final(const double* __restrict__ pool, const float* __restrict__ wfc,
                        const float* __restrict__ fcb, float* __restrict__ out, double invN) {
    __shared__ double s[256];
    int t = threadIdx.x;
    s[t] = pool[t];
    __syncthreads();
    for (int o = 128; o > 0; o >>= 1) {
        if (t < o) s[t] += s[t + o];
        __syncthreads();
    }
    if (t == 0) out[0] = (float)(s[0] * invN) + wfc[64] + fcb[0];
}

extern "C" void kernel_launch(void* const* d_in, const int* in_sizes, int n_in,
                              void* d_out, int out_size, void* d_ws, size_t ws_size,
                              hipStream_t stream) {
    const float* x   = (const float*)d_in[0];
    const int*   ei  = (const int*)d_in[1];
    const float* W1  = (const float*)d_in[2];
    const float* b1  = (const float*)d_in[3];
    const float* W2  = (const float*)d_in[4];
    const float* b2  = (const float*)d_in[5];
    const float* W3  = (const float*)d_in[6];
    const float* b3  = (const float*)d_in[7];
    const float* fcW = (const float*)d_in[8];
    const float* fcb = (const float*)d_in[9];

    const int N = in_sizes[0] / 10;
    const int E = in_sizes[1] / 2;
    const int* src = ei;
    const int* dst = ei + E;

    // ---- workspace carve-up (256B aligned) ----
    char* w = (char*)d_ws;
    size_t off = 0;
    auto alloc = [&](size_t bytes) -> void* {
        void* p = w + off;
        off += (bytes + 255) & ~(size_t)255;
        return p;
    };
    // cnt + pool adjacent: one memset zeroes both
    int*    cnt       = (int*)alloc((size_t)N * 4);
    double* pool      = (double*)alloc(256 * 8);
    size_t  zeroBytes = off;                         // covers cnt (+pad) + pool
    float*  dinv      = (float*)alloc((size_t)N * 4);
    int*    rowptr    = (int*)alloc((size_t)(N + 1) * 4);
    int*    cursor    = (int*)alloc((size_t)N * 4);
    int*    col       = (int*)alloc((size_t)E * 4);
    int*    blockSums = (int*)alloc(256 * 4);
    float*  wfc       = (float*)alloc(65 * 4);
    float*  tvec      = (float*)alloc((size_t)N * 4);
    __half* gx        = (__half*)alloc((size_t)N * 10 * 2);
    __half* g1        = (__half*)alloc((size_t)N * 64 * 2);
    (void)ws_size; (void)n_in; (void)out_size;

    const int nbScan   = (N + 255) / 256;
    const int nbEdges  = (E + 255) / 256;
    const int nbNode16 = (N + 15) / 16;       // 16 nodes per 256-block
    const int Q8       = (N + 7) / 8;         // dst-range width for XCD-pinned fill

    // ---- preprocessing ----
    hipMemsetAsync(cnt, 0, zeroBytes, stream);
    k_deg  <<<nbEdges, 256, 0, stream>>>(dst, E, cnt);
    k_scanA<<<nbScan, 256, 0, stream>>>(cnt, N, blockSums);
    k_scan2<<<1, 256, 0, stream>>>(blockSums, nbScan);
    k_scanC<<<nbScan, 256, 0, stream>>>(cnt, N, blockSums, x, rowptr, cursor, dinv, gx);
    k_fillX<<<nbEdges * 8, 256, 0, stream>>>(src, dst, E, cursor, col, Q8);
    k_wfc  <<<1, 64, 0, stream>>>(W3, fcW, b3, wfc);

    // ---- fused layers ----
    k_L1<<<nbNode16, 256, 0, stream>>>(gx, W1, b1, rowptr, col, dinv, g1, N);
    k_L2<<<nbNode16, 256, 0, stream>>>(g1, W2, b2, wfc, rowptr, col, dinv, tvec, N);
    k_agg3<<<nbNode16, 256, 0, stream>>>(tvec, rowptr, col, dinv, pool, N);
    k_final<<<1, 256, 0, stream>>>(pool, wfc, fcb, (float*)d_out, 1.0 / (double)N);
}